// Round 4
// baseline (173.051 us; speedup 1.0000x reference)
//
#include <hip/hip_runtime.h>

#define L_IN   32768
#define L_OUT  32766   // (32768 - 3) + 1
#define C_IN   32
#define C_OUT  32
#define KW     3
#define TILE_L 512     // l span per block: 64 lanes x 8
#define NTILES 64      // 32768 / 512

// ---- prekernel: transpose weights [co][ci][k] -> ws[ci][co][k] (3072 floats)
__global__ void transpose_w(const float* __restrict__ w, float* __restrict__ ws) {
    int i = blockIdx.x * 256 + threadIdx.x;
    if (i < C_IN * C_OUT * KW) {
        int ci = i / (C_OUT * KW);
        int r  = i - ci * (C_OUT * KW);
        int co = r / KW;
        int k  = r - co * KW;
        ws[i] = w[co * (C_IN * KW) + ci * KW + k];
    }
}

__global__ __launch_bounds__(256) void conv1d_valu(
    const float* __restrict__ x, const float* __restrict__ ws,
    float* __restrict__ out)
{
    const int tid  = threadIdx.x;
    const int lane = tid & 63;
    // wave-uniform co group; readfirstlane makes it provably uniform -> s_load weights
    const int co0  = __builtin_amdgcn_readfirstlane((tid >> 6) << 3);
    const int blk  = blockIdx.x;          // 0..1023
    const int b    = blk >> 6;            // / NTILES
    const int tile = blk & (NTILES - 1);
    const int l0   = tile * TILE_L + lane * 8;   // first output l for this thread

    const float* xr = x + (size_t)b * C_IN * L_IN + l0;

    float acc[8][8];
#pragma unroll
    for (int c = 0; c < 8; ++c)
#pragma unroll
        for (int j = 0; j < 8; ++j) acc[c][j] = 0.f;

#pragma unroll 2
    for (int ci = 0; ci < C_IN; ++ci) {
        // ---- x: 12 floats covering l0..l0+11 (need l0..l0+9), coalesced float4
        float xv[12];
        const float* xp = xr + (size_t)ci * L_IN;
        if (l0 + 11 < L_IN) {
#pragma unroll
            for (int q = 0; q < 3; ++q) {
                float4 t = *(const float4*)(xp + q * 4);
                xv[q*4+0] = t.x; xv[q*4+1] = t.y; xv[q*4+2] = t.z; xv[q*4+3] = t.w;
            }
        } else {            // only lane 63 of the last tile per batch
#pragma unroll
            for (int j = 0; j < 12; ++j)
                xv[j] = (l0 + j < L_IN) ? xp[j] : 0.f;
        }

        // ---- weights: uniform address -> scalar loads, 24 consecutive floats
        const float* wr = ws + ci * (C_OUT * KW) + co0 * KW;
        float wv[24];
#pragma unroll
        for (int q = 0; q < 6; ++q) {
            float4 t = *(const float4*)(wr + q * 4);
            wv[q*4+0] = t.x; wv[q*4+1] = t.y; wv[q*4+2] = t.z; wv[q*4+3] = t.w;
        }

#pragma unroll
        for (int c = 0; c < 8; ++c)
#pragma unroll
            for (int j = 0; j < 8; ++j)
#pragma unroll
                for (int k = 0; k < KW; ++k)
                    acc[c][j] = fmaf(wv[c * KW + k], xv[j + k], acc[c][j]);
    }

    // ---- store: 8 consecutive l per row, float2 (row stride 32766 -> 8B align)
    float* ob = out + ((size_t)b * C_OUT + co0) * L_OUT + l0;
#pragma unroll
    for (int c = 0; c < 8; ++c) {
        if (l0 + 7 < L_OUT) {
#pragma unroll
            for (int q = 0; q < 4; ++q)
                *(float2*)(ob + q * 2) = make_float2(acc[c][2*q], acc[c][2*q+1]);
        } else {            // tail: l0=32760 -> 6 valid outputs
#pragma unroll
            for (int j = 0; j < 8; ++j)
                if (l0 + j < L_OUT) ob[j] = acc[c][j];
        }
        ob += L_OUT;
    }
}

extern "C" void kernel_launch(void* const* d_in, const int* in_sizes, int n_in,
                              void* d_out, int out_size, void* d_ws, size_t ws_size,
                              hipStream_t stream) {
    const float* x = (const float*)d_in[0];
    const float* w = (const float*)d_in[1];
    float* out     = (float*)d_out;
    float* ws      = (float*)d_ws;    // 3072 floats = 12 KB scratch

    transpose_w<<<dim3(12), 256, 0, stream>>>(w, ws);
    conv1d_valu<<<dim3(16 * NTILES), 256, 0, stream>>>(x, ws, out);
}

// Round 5
// 131.823 us; speedup vs baseline: 1.3128x; 1.3128x over previous
//
#include <hip/hip_runtime.h>

#define L_IN   32768
#define L_OUT  32766   // (32768 - 3) + 1
#define C_IN   32
#define C_OUT  32
#define KW     3
#define TILE_L 256               // output positions per block
#define XROW   260               // 256 + 2 halo, padded to float4 multiple
#define NTILES 128               // 32768 / 256

// ---- prekernel: w[co][ci][k] -> wt[g][ci][co_local*3+k], g = co>>3 (per-wave stream)
__global__ void transpose_w(const float* __restrict__ w, float* __restrict__ wt) {
    int i = blockIdx.x * 256 + threadIdx.x;      // 0..3071
    if (i < C_IN * C_OUT * KW) {
        int g  = i / 768;
        int r  = i - g * 768;
        int ci = r / 24;
        int t  = r - ci * 24;
        int cl = t / 3;
        int k  = t - cl * 3;
        wt[i] = w[(g * 8 + cl) * (C_IN * KW) + ci * KW + k];
    }
}

__global__ __launch_bounds__(256, 4) void conv1d_hybrid(
    const float* __restrict__ x, const float* __restrict__ wt,
    float* __restrict__ out)
{
    __shared__ __attribute__((aligned(16))) float xs[C_IN * XROW];   // 33.3 KB

    const int tid       = threadIdx.x;
    const int lane      = tid & 63;
    const int w         = tid >> 6;            // wave id in block, 0..3
    const int blk       = blockIdx.x;
    const int b         = blk >> 7;
    const int tile      = blk & (NTILES - 1);
    const int tile_base = tile << 8;

    const float* xb = x + (size_t)b * C_IN * L_IN;

    // ---- stage main 256 floats of each row via async global->LDS (width 16)
    // wave w stages rows 8w..8w+7; one instr per row: lanes cover 1024 B
#pragma unroll
    for (int r = 0; r < 8; ++r) {
        const int row = w * 8 + r;
        const float* src = xb + (size_t)row * L_IN + tile_base + lane * 4;
        __builtin_amdgcn_global_load_lds(
            (const __attribute__((address_space(1))) void*)src,
            (__attribute__((address_space(3))) void*)&xs[row * XROW],
            16, 0, 0);
    }

    // ---- halo: cols 256,257 of each row (32 rows, threads 0..31)
    if (tid < C_IN) {
        float2 h = make_float2(0.f, 0.f);
        if (tile_base + 257 < L_IN)    // false only for tile==127 (both cols OOB)
            h = *(const float2*)(xb + (size_t)tid * L_IN + tile_base + 256);
        xs[tid * XROW + 256] = h.x;
        xs[tid * XROW + 257] = h.y;
    }
    __syncthreads();

    // ---- compute: 8 co x 4 l per thread; weights via uniform (scalar) loads
    const int g  = __builtin_amdgcn_readfirstlane(w);   // co group, provably uniform
    const int l0 = lane * 4;

    float acc[8][4];
#pragma unroll
    for (int c = 0; c < 8; ++c)
#pragma unroll
        for (int j = 0; j < 4; ++j) acc[c][j] = 0.f;

    const float* xp = &xs[l0];
    const float* wr = wt + g * (C_IN * 24);

#pragma unroll 4
    for (int ci = 0; ci < C_IN; ++ci) {
        float xv[6];
        float4 xa = *(const float4*)(xp);
        float2 xc = *(const float2*)(xp + 4);
        xv[0] = xa.x; xv[1] = xa.y; xv[2] = xa.z; xv[3] = xa.w;
        xv[4] = xc.x; xv[5] = xc.y;

        float wv[24];   // uniform address -> s_load, stays in SGPRs
#pragma unroll
        for (int q = 0; q < 6; ++q) {
            float4 t = *(const float4*)(wr + q * 4);
            wv[q*4+0] = t.x; wv[q*4+1] = t.y; wv[q*4+2] = t.z; wv[q*4+3] = t.w;
        }

#pragma unroll
        for (int c = 0; c < 8; ++c)
#pragma unroll
            for (int j = 0; j < 4; ++j)
#pragma unroll
                for (int k = 0; k < KW; ++k)
                    acc[c][j] = fmaf(wv[c * KW + k], xv[j + k], acc[c][j]);

        xp += XROW;
        wr += 24;
    }

    // ---- store: float2 pairs (row stride 32766 floats -> 8 B alignment)
    const int lg = tile_base + l0;
    float* ob = out + ((size_t)b * C_OUT + g * 8) * L_OUT + lg;
#pragma unroll
    for (int c = 0; c < 8; ++c) {
        *(float2*)(ob) = make_float2(acc[c][0], acc[c][1]);   // lg+1 <= 32765 always
        if (lg + 3 < L_OUT)
            *(float2*)(ob + 2) = make_float2(acc[c][2], acc[c][3]);
        else if (lg + 2 < L_OUT)
            ob[2] = acc[c][2];
        ob += L_OUT;
    }
}

extern "C" void kernel_launch(void* const* d_in, const int* in_sizes, int n_in,
                              void* d_out, int out_size, void* d_ws, size_t ws_size,
                              hipStream_t stream) {
    const float* x = (const float*)d_in[0];
    const float* w = (const float*)d_in[1];
    float* out     = (float*)d_out;
    float* wt      = (float*)d_ws;    // 3072 floats = 12 KB scratch

    transpose_w<<<dim3(12), 256, 0, stream>>>(w, wt);
    conv1d_hybrid<<<dim3(16 * NTILES), 256, 0, stream>>>(x, wt, out);
}